// Round 1
// 763.659 us; speedup vs baseline: 1.0665x; 1.0665x over previous
//
#include <hip/hip_runtime.h>

#define BT 4096
#define H  2048
#define V  32000
#define BM 256
#define BN 256
#define BKB 128                   /* fp8 bytes per K-tile row */
#define KT (H / BKB)              /* 16 K-tiles */
#define NTILES (V / BN)           /* 125 */
#define MTILES (BT / BM)          /* 16 */
#define NWG (MTILES * NTILES)     /* 2000, % 8 == 0 -> bijective XCD swizzle */
#define IGNORE_INDEX (-100)

typedef int   v8i   __attribute__((ext_vector_type(8)));
typedef float f32x4 __attribute__((ext_vector_type(4)));

#define SCALE_ONE 0x7F7F7F7F        /* E8M0 127 = 2^0 in every byte */
#define UNSCALE   (1.0f / 65536.0f) /* inputs pre-scaled by 2^8 each */

#define BAR()   __builtin_amdgcn_s_barrier()
#define LGKM0() asm volatile("s_waitcnt lgkmcnt(0)" ::: "memory")
#define LGKM8() asm volatile("s_waitcnt lgkmcnt(8)" ::: "memory")
#define VMC(N)  asm volatile("s_waitcnt vmcnt(" #N ")" ::: "memory")

__device__ inline void load_lds16(const void* g, void* l) {
  __builtin_amdgcn_global_load_lds(
      (const __attribute__((address_space(1))) unsigned int*)g,
      (__attribute__((address_space(3))) unsigned int*)l,
      16, 0, 0);
}

// ---------------------------------------------------------- fp32 -> fp8 e4m3
__global__ __launch_bounds__(256)
void cvt_fp8_kernel(const float* __restrict__ in, unsigned int* __restrict__ out, long n8) {
  long i = (long)blockIdx.x * blockDim.x + threadIdx.x;
  long stride = (long)gridDim.x * blockDim.x;
  for (; i < n8; i += stride) {
    float4 x = ((const float4*)in)[2 * i];
    float4 y = ((const float4*)in)[2 * i + 1];
    int lo = 0, hi = 0;
    lo = __builtin_amdgcn_cvt_pk_fp8_f32(x.x * 256.f, x.y * 256.f, lo, false);
    lo = __builtin_amdgcn_cvt_pk_fp8_f32(x.z * 256.f, x.w * 256.f, lo, true);
    hi = __builtin_amdgcn_cvt_pk_fp8_f32(y.x * 256.f, y.y * 256.f, hi, false);
    hi = __builtin_amdgcn_cvt_pk_fp8_f32(y.z * 256.f, y.w * 256.f, hi, true);
    uint2 p; p.x = (unsigned)lo; p.y = (unsigned)hi;
    ((uint2*)out)[i] = p;
  }
}

// --------------------------------------------------------------------------
// 256x256-tile, 8-wave (2x4), 8-phase K-loop with counted vmcnt (T3+T4),
// XOR-8 chunk LDS swizzle (T2), setprio around MFMA clusters (T5),
// bijective XCD blockIdx swizzle (T1). MX-fp8 16x16x128 MFMA.
// Schedule follows the m194-m204-verified 8-phase template:
//   per phase: {ds_read subtile | 1 half-tile global_load_lds | bar |
//               lgkmcnt(0) | setprio(1) 8xMFMA setprio(0) | bar}
//   vmcnt(6) only before the closing barrier of phases 3 and 7.
// --------------------------------------------------------------------------
union frag_u { v8i v; int4 h[2]; };

#define MF(C, A, B)                                                         \
  (C) = __builtin_amdgcn_mfma_scale_f32_16x16x128_f8f6f4(                   \
      (A).v, (B).v, (C), 0, 0, 0, SCALE_ONE, 0, SCALE_ONE)

__global__ __launch_bounds__(512, 2)
void gemm_lse_kernel(const unsigned char* __restrict__ Af8,
                     const unsigned char* __restrict__ Bf8,
                     const int* __restrict__ tgt,
                     float* __restrict__ pm, float* __restrict__ pl,
                     float* __restrict__ tl) {
  __shared__ __align__(16) unsigned char As[2][BM][BKB];  // 64 KB
  __shared__ __align__(16) unsigned char Bs[2][BN][BKB];  // 64 KB
  __shared__ float red_m[4][BM];
  __shared__ float red_l[4][BM];
  __shared__ int   stgt[BM];

  // T1: bijective XCD swizzle (2000 % 8 == 0). mt fastest -> 16 consecutive
  // blocks on one XCD share a B-panel (L2-resident); A is L3-resident.
  const int wgid = ((int)blockIdx.x & 7) * (NWG / 8) + ((int)blockIdx.x >> 3);
  const int mt = wgid & (MTILES - 1);
  const int nt = wgid / MTILES;
  const int m0 = mt * BM;
  const int n0 = nt * BN;

  const int tid  = threadIdx.x;
  const int lane = tid & 63;
  const int w    = tid >> 6;   // wave 0..7
  const int wr   = w >> 2;     // 0..1 : rows [wr*128, +128)
  const int wc   = w & 3;      // 0..3 : cols [wc*64, +64)
  const int lm   = lane & 15;
  const int q    = lane >> 4;  // k-chunk selector

  if (tid < BM) stgt[tid] = tgt[m0 + tid];
  __syncthreads();  // drains stgt's vmcnt before counted staging begins

  // staging: wave w stages rows [w*16, w*16+16) of each 128-row half-tile,
  // 2 x global_load_lds (8 rows each). LDS dest is linear; the XOR-8 chunk
  // swizzle is applied on the GLOBAL source address (both-sides rule, m201):
  // slot c of LDS row r holds global chunk c ^ (r&7); r&7 == lane>>3 here.
  const int srow = lane >> 3;
  const int gch  = ((lane & 7) ^ srow) * 16;
  const unsigned char* aSrc = Af8 + (size_t)(m0 + w * 16 + srow) * H + gch;
  const unsigned char* bSrc = Bf8 + (size_t)(n0 + w * 16 + srow) * H + gch;

  auto stageA = [&](int buf, int hf, int kt) {
    const unsigned char* s = aSrc + (size_t)hf * 128 * H + (size_t)kt * BKB;
    unsigned char* d = &As[buf][hf * 128 + w * 16][0];
    load_lds16(s, d);
    load_lds16(s + (size_t)8 * H, d + 8 * BKB);
  };
  auto stageB = [&](int buf, int hf, int kt) {
    const unsigned char* s = bSrc + (size_t)hf * 128 * H + (size_t)kt * BKB;
    unsigned char* d = &Bs[buf][hf * 128 + w * 16][0];
    load_lds16(s, d);
    load_lds16(s + (size_t)8 * H, d + 8 * BKB);
  };

  // fragment reads: row r = (wr*128|wc*64) + f*16 + lm, chunks 2q, 2q+1,
  // swizzled slots (2q)^(lm&7), (2q+1)^(lm&7)  (r&7 == lm&7).
  const int c0 = ((2 * q)     ^ (lm & 7)) * 16;
  const int c1 = ((2 * q + 1) ^ (lm & 7)) * 16;
  const unsigned char* aRdB = &As[0][wr * 128 + lm][0];
  const unsigned char* bRdB = &Bs[0][wc * 64 + lm][0];

  auto ldA = [&](frag_u& f, int buf, int ai) {
    const unsigned char* p = aRdB + buf * (BM * BKB) + ai * (16 * BKB);
    f.h[0] = *(const int4*)(p + c0);
    f.h[1] = *(const int4*)(p + c1);
  };
  auto ldB = [&](frag_u& f, int buf, int bj) {
    const unsigned char* p = bRdB + buf * (BN * BKB) + bj * (16 * BKB);
    f.h[0] = *(const int4*)(p + c0);
    f.h[1] = *(const int4*)(p + c1);
  };

  f32x4 acc[8][4];
#pragma unroll
  for (int a = 0; a < 8; ++a)
#pragma unroll
    for (int b = 0; b < 4; ++b) acc[a][b] = (f32x4){0.f, 0.f, 0.f, 0.f};

  frag_u fa0, fa1, fa2, fa3, fb0, fb1, fb2, fb3;

  // ---- prologue: tile0 (buf0) fully + tile1 A0,A1,B0 -> 3 half-tiles in flight
  stageA(0, 0, 0); stageA(0, 1, 0); stageB(0, 0, 0); stageB(0, 1, 0);
  VMC(4);
  stageA(1, 0, 1); stageA(1, 1, 1); stageB(1, 0, 1);
  VMC(6);
  BAR();

  for (int i = 0; i < 8; ++i) {
    const int t0 = 2 * i, t1 = 2 * i + 1;
    const bool pre = (i < 7);

    // ---- phase 0: tile t0 (buf0), a0-3 x b0-1
    ldA(fa0, 0, 0); ldA(fa1, 0, 1); ldA(fa2, 0, 2); ldA(fa3, 0, 3);
    ldB(fb0, 0, 0); ldB(fb1, 0, 1);
    stageB(1, 1, t1);                       // B1 of tile t1
    LGKM8();
    BAR(); LGKM0();
    __builtin_amdgcn_s_setprio(1);
    MF(acc[0][0], fa0, fb0); MF(acc[1][0], fa1, fb0);
    MF(acc[2][0], fa2, fb0); MF(acc[3][0], fa3, fb0);
    MF(acc[0][1], fa0, fb1); MF(acc[1][1], fa1, fb1);
    MF(acc[2][1], fa2, fb1); MF(acc[3][1], fa3, fb1);
    __builtin_amdgcn_s_setprio(0);
    BAR();

    // ---- phase 1: a0-3 x b2-3
    ldB(fb2, 0, 2); ldB(fb3, 0, 3);
    if (pre) stageA(0, 0, t0 + 2);          // A0 of tile t0+2
    BAR(); LGKM0();
    __builtin_amdgcn_s_setprio(1);
    MF(acc[0][2], fa0, fb2); MF(acc[1][2], fa1, fb2);
    MF(acc[2][2], fa2, fb2); MF(acc[3][2], fa3, fb2);
    MF(acc[0][3], fa0, fb3); MF(acc[1][3], fa1, fb3);
    MF(acc[2][3], fa2, fb3); MF(acc[3][3], fa3, fb3);
    __builtin_amdgcn_s_setprio(0);
    BAR();

    // ---- phase 2: a4-7 x b0-1
    ldA(fa0, 0, 4); ldA(fa1, 0, 5); ldA(fa2, 0, 6); ldA(fa3, 0, 7);
    if (pre) stageA(0, 1, t0 + 2);          // A1 of tile t0+2
    BAR(); LGKM0();
    __builtin_amdgcn_s_setprio(1);
    MF(acc[4][0], fa0, fb0); MF(acc[5][0], fa1, fb0);
    MF(acc[6][0], fa2, fb0); MF(acc[7][0], fa3, fb0);
    MF(acc[4][1], fa0, fb1); MF(acc[5][1], fa1, fb1);
    MF(acc[6][1], fa2, fb1); MF(acc[7][1], fa3, fb1);
    __builtin_amdgcn_s_setprio(0);
    BAR();

    // ---- phase 3: a4-7 x b2-3
    if (pre) stageB(0, 0, t0 + 2);          // B0 of tile t0+2
    BAR(); LGKM0();
    __builtin_amdgcn_s_setprio(1);
    MF(acc[4][2], fa0, fb2); MF(acc[5][2], fa1, fb2);
    MF(acc[6][2], fa2, fb2); MF(acc[7][2], fa3, fb2);
    MF(acc[4][3], fa0, fb3); MF(acc[5][3], fa1, fb3);
    MF(acc[6][3], fa2, fb3); MF(acc[7][3], fa3, fb3);
    __builtin_amdgcn_s_setprio(0);
    if (pre) { VMC(6); } else { VMC(0); }   // tile t1 landed (all waves after bar)
    BAR();

    // ---- phase 4: tile t1 (buf1), a0-3 x b0-1
    ldA(fa0, 1, 0); ldA(fa1, 1, 1); ldA(fa2, 1, 2); ldA(fa3, 1, 3);
    ldB(fb0, 1, 0); ldB(fb1, 1, 1);
    if (pre) stageB(0, 1, t0 + 2);          // B1 of tile t0+2
    LGKM8();
    BAR(); LGKM0();
    __builtin_amdgcn_s_setprio(1);
    MF(acc[0][0], fa0, fb0); MF(acc[1][0], fa1, fb0);
    MF(acc[2][0], fa2, fb0); MF(acc[3][0], fa3, fb0);
    MF(acc[0][1], fa0, fb1); MF(acc[1][1], fa1, fb1);
    MF(acc[2][1], fa2, fb1); MF(acc[3][1], fa3, fb1);
    __builtin_amdgcn_s_setprio(0);
    BAR();

    // ---- phase 5: a0-3 x b2-3
    ldB(fb2, 1, 2); ldB(fb3, 1, 3);
    if (pre) stageA(1, 0, t1 + 2);          // A0 of tile t1+2
    BAR(); LGKM0();
    __builtin_amdgcn_s_setprio(1);
    MF(acc[0][2], fa0, fb2); MF(acc[1][2], fa1, fb2);
    MF(acc[2][2], fa2, fb2); MF(acc[3][2], fa3, fb2);
    MF(acc[0][3], fa0, fb3); MF(acc[1][3], fa1, fb3);
    MF(acc[2][3], fa2, fb3); MF(acc[3][3], fa3, fb3);
    __builtin_amdgcn_s_setprio(0);
    BAR();

    // ---- phase 6: a4-7 x b0-1
    ldA(fa0, 1, 4); ldA(fa1, 1, 5); ldA(fa2, 1, 6); ldA(fa3, 1, 7);
    if (pre) stageA(1, 1, t1 + 2);          // A1 of tile t1+2
    BAR(); LGKM0();
    __builtin_amdgcn_s_setprio(1);
    MF(acc[4][0], fa0, fb0); MF(acc[5][0], fa1, fb0);
    MF(acc[6][0], fa2, fb0); MF(acc[7][0], fa3, fb0);
    MF(acc[4][1], fa0, fb1); MF(acc[5][1], fa1, fb1);
    MF(acc[6][1], fa2, fb1); MF(acc[7][1], fa3, fb1);
    __builtin_amdgcn_s_setprio(0);
    BAR();

    // ---- phase 7: a4-7 x b2-3
    if (pre) stageB(1, 0, t1 + 2);          // B0 of tile t1+2
    BAR(); LGKM0();
    __builtin_amdgcn_s_setprio(1);
    MF(acc[4][2], fa0, fb2); MF(acc[5][2], fa1, fb2);
    MF(acc[6][2], fa2, fb2); MF(acc[7][2], fa3, fb2);
    MF(acc[4][3], fa0, fb3); MF(acc[5][3], fa1, fb3);
    MF(acc[6][3], fa2, fb3); MF(acc[7][3], fa3, fb3);
    __builtin_amdgcn_s_setprio(0);
    if (pre) VMC(6);                        // tile t0+2 landed
    BAR();
  }

  __syncthreads();

  // ---- target-logit extraction (C layout: col=lane&15, row=q*4+reg)
#pragma unroll
  for (int ai = 0; ai < 8; ++ai) {
#pragma unroll
    for (int r = 0; r < 4; ++r) {
      int row_local = wr * 128 + ai * 16 + q * 4 + r;
      int c = stgt[row_local] - n0 - wc * 64;
      if ((unsigned)c < 64u && (c & 15) == lm) {
        int bj = c >> 4;
        float v = bj == 0 ? acc[ai][0][r]
                : bj == 1 ? acc[ai][1][r]
                : bj == 2 ? acc[ai][2][r]
                :           acc[ai][3][r];
        tl[m0 + row_local] = v * UNSCALE;
      }
    }
  }

  // ---- per-row (max, sumexp) over this wave's 64 columns
#pragma unroll
  for (int ai = 0; ai < 8; ++ai) {
#pragma unroll
    for (int r = 0; r < 4; ++r) {
      float v0 = acc[ai][0][r] * UNSCALE;
      float v1 = acc[ai][1][r] * UNSCALE;
      float v2 = acc[ai][2][r] * UNSCALE;
      float v3 = acc[ai][3][r] * UNSCALE;
      float mx = fmaxf(fmaxf(v0, v1), fmaxf(v2, v3));
#pragma unroll
      for (int off = 1; off < 16; off <<= 1) mx = fmaxf(mx, __shfl_xor(mx, off));
      float s = __expf(v0 - mx) + __expf(v1 - mx) + __expf(v2 - mx) + __expf(v3 - mx);
#pragma unroll
      for (int off = 1; off < 16; off <<= 1) s += __shfl_xor(s, off);
      if (lm == 0) {
        int row_local = wr * 128 + ai * 16 + q * 4 + r;
        red_m[wc][row_local] = mx;
        red_l[wc][row_local] = s;
      }
    }
  }
  __syncthreads();
  if (tid < BM) {
    float M = fmaxf(fmaxf(red_m[0][tid], red_m[1][tid]),
                    fmaxf(red_m[2][tid], red_m[3][tid]));
    float L = red_l[0][tid] * __expf(red_m[0][tid] - M)
            + red_l[1][tid] * __expf(red_m[1][tid] - M)
            + red_l[2][tid] * __expf(red_m[2][tid] - M)
            + red_l[3][tid] * __expf(red_m[3][tid] - M);
    long idx = (long)nt * BT + (m0 + tid);
    pm[idx] = M;
    pl[idx] = L;
  }
}

// -------------------------------------------- combine partials, wave per row
__global__ __launch_bounds__(256)
void row_lse_kernel(const float* __restrict__ pm, const float* __restrict__ pl,
                    const float* __restrict__ tl, const int* __restrict__ tgt,
                    float* __restrict__ rl) {
  int row  = blockIdx.x * 4 + (threadIdx.x >> 6);
  int lane = threadIdx.x & 63;
  float M = -__builtin_inff();
  float L = 0.f;
  for (int t = lane; t < NTILES; t += 64) {
    float m2 = pm[(long)t * BT + row];
    float l2 = pl[(long)t * BT + row];
    float Mn = fmaxf(M, m2);
    L = L * __expf(M - Mn) + l2 * __expf(m2 - Mn);
    M = Mn;
  }
#pragma unroll
  for (int off = 1; off < 64; off <<= 1) {
    float m2 = __shfl_xor(M, off);
    float l2 = __shfl_xor(L, off);
    float Mn = fmaxf(M, m2);
    L = L * __expf(M - Mn) + l2 * __expf(m2 - Mn);
    M = Mn;
  }
  if (lane == 0) {
    float lse = M + logf(L);
    int t = tgt[row];
    rl[row] = (t != IGNORE_INDEX) ? (lse - tl[row]) : 0.f;
  }
}

// ------------------------------------------------------------- final reduce
__global__ __launch_bounds__(256)
void final_kernel(const float* __restrict__ rl, const int* __restrict__ tgt,
                  float* __restrict__ out) {
  __shared__ float ss[4];
  __shared__ float sc[4];
  float s = 0.f, c = 0.f;
  for (int r = threadIdx.x; r < BT; r += 256) {
    s += rl[r];
    c += (tgt[r] != IGNORE_INDEX) ? 1.f : 0.f;
  }
#pragma unroll
  for (int off = 32; off > 0; off >>= 1) {
    s += __shfl_xor(s, off);
    c += __shfl_xor(c, off);
  }
  int w = threadIdx.x >> 6;
  if ((threadIdx.x & 63) == 0) { ss[w] = s; sc[w] = c; }
  __syncthreads();
  if (threadIdx.x == 0) {
    float S = ss[0] + ss[1] + ss[2] + ss[3];
    float C = sc[0] + sc[1] + sc[2] + sc[3];
    out[0] = S / fmaxf(C, 1.f);
  }
}

extern "C" void kernel_launch(void* const* d_in, const int* in_sizes, int n_in,
                              void* d_out, int out_size, void* d_ws, size_t ws_size,
                              hipStream_t stream) {
  const float* hs  = (const float*)d_in[0];   // hidden_states [BT][H] fp32
  const float* wt  = (const float*)d_in[1];   // weight [V][H] fp32
  const int*   tgt = (const int*)d_in[2];     // targets [BT]
  float*       out = (float*)d_out;

  char* ws = (char*)d_ws;
  size_t off = 0;
  auto alloc = [&](size_t bytes) -> void* {
    void* p = ws + off;
    off += (bytes + 255) & ~(size_t)255;
    return p;
  };
  unsigned char* wf8 = (unsigned char*)alloc((size_t)V * H);        // 65.5 MB
  unsigned char* hf8 = (unsigned char*)alloc((size_t)BT * H);       // 8.4 MB
  float* pm = (float*)alloc((size_t)NTILES * BT * 4);               // 2.0 MB
  float* pl = (float*)alloc((size_t)NTILES * BT * 4);               // 2.0 MB
  float* tl = (float*)alloc((size_t)BT * 4);
  float* rl = (float*)alloc((size_t)BT * 4);
  (void)ws_size; (void)in_sizes; (void)n_in; (void)out_size;

  cvt_fp8_kernel<<<8192, 256, 0, stream>>>(wt, (unsigned int*)wf8, (long)V * H / 8);
  cvt_fp8_kernel<<<1024, 256, 0, stream>>>(hs, (unsigned int*)hf8, (long)BT * H / 8);

  gemm_lse_kernel<<<NWG, 512, 0, stream>>>(hf8, wf8, tgt, pm, pl, tl);

  row_lse_kernel<<<BT / 4, 256, 0, stream>>>(pm, pl, tl, tgt, rl);
  final_kernel<<<1, 256, 0, stream>>>(rl, tgt, out);
}